// Round 4
// baseline (110.323 us; speedup 1.0000x reference)
//
#include <hip/hip_runtime.h>
#include <math.h>

#define BATCH 8
#define NSEQ  4096
#define NWIN  65
#define OUTD  64
#define NB    21

typedef __attribute__((ext_vector_type(2))) float f32x2;

// out[b,o,w,s] = a(b,s) * ( const0*coefs[o,0] + sum_{n=1..10} scale*(sin(n*th)*coefs[o,2n-1] + cos(n*th)*coefs[o,2n]) )
// th = (2*pi/78) * c(b,s) * ((w+7) - bshift(b,s))
// Thread: 2 consecutive s-points, 64 o-outputs in groups of 4 interleaved chains.
// 2 pts/thread keeps basis at 42 VGPRs -> target 6 waves/SIMD for store/VALU overlap.
__global__ __launch_bounds__(256, 6) void trf_kernel(
    const float* __restrict__ x,        // (8,1,4096)
    const float* __restrict__ conv_w,   // (3,1,2)
    const float* __restrict__ conv_b,   // (3,)
    const float* __restrict__ coefs,    // (64,1,21)
    float* __restrict__ out)            // (8,64,65,4096)
{
    const int tid   = threadIdx.x;
    const int blk   = blockIdx.x;
    const int chunk = blk & 7;           // 8 chunks of 512 s each
    const int bw    = blk >> 3;
    const int w     = bw % NWIN;
    const int b     = bw / NWIN;
    const int s0    = chunk * 512 + tid * 2;

    // conv weights: wave-uniform scalar loads
    const float w00 = conv_w[0], w01 = conv_w[1];
    const float w10 = conv_w[2], w11 = conv_w[3];
    const float w20 = conv_w[4], w21 = conv_w[5];
    const float cb0 = conv_b[0], cb1 = conv_b[1], cb2 = conv_b[2];

    const float* xb = x + (size_t)b * NSEQ;
    const f32x2 xq  = *(const f32x2*)(xb + s0);            // x[s0..s0+1], 8B aligned
    const float xm0 = (s0 > 0) ? xb[s0 - 1] : 0.0f;        // causal left-pad

    const float K      = 0.08055365778435367f;  // 2*pi/78
    const float SCALE  = 0.16012815380508713f;  // 1/sqrt(39)
    const float CONST0 = 0.11322770341445958f;  // 1/(sqrt(2)*sqrt(39))
    const float wl     = (float)(w + 7);

    f32x2 basis[NB];                                       // 42 VGPRs, static-indexed
#pragma unroll
    for (int p = 0; p < 2; ++p) {
        const float xm = (p == 0) ? xm0 : xq[0];
        const float xc = xq[p];
        const float p0 = fmaf(xm, w00, fmaf(xc, w01, cb0));
        const float p1 = fmaf(xm, w10, fmaf(xc, w11, cb1));
        const float p2 = fmaf(xm, w20, fmaf(xc, w21, cb2));
        const float a  = fabsf(p0);
        const float bs = fminf(fmaxf(p1, -7.0f), 7.0f);
        const float c  = fminf(fmaxf(1.0f + p2, 0.5f), 1.4f);

        const float theta = K * c * (wl - bs);
        float sn, cn;
        __sincosf(theta, &sn, &cn);

        const float fa = a * SCALE;
        basis[0][p] = a * CONST0;
        const float twoc = 2.0f * cn;
        float sp = 0.0f, cp = 1.0f;      // sin(0), cos(0)
        float scur = sn, ccur = cn;      // sin(th), cos(th)
#pragma unroll
        for (int n = 1; n <= 10; ++n) {  // Chebyshev recurrence for sin/cos(n*th)
            basis[2 * n - 1][p] = fa * scur;
            basis[2 * n][p]     = fa * ccur;
            const float snew = fmaf(twoc, scur, -sp);
            const float cnew = fmaf(twoc, ccur, -cp);
            sp = scur; cp = ccur; scur = snew; ccur = cnew;
        }
    }

    // out index: ((b*64 + o)*65 + w)*4096 + s0
    float* op = out + ((size_t)b * OUTD * NWIN + (size_t)w) * NSEQ + s0;
    const size_t ostride = (size_t)NWIN * NSEQ;

    // 4 interleaved accumulator chains per group of 4 outputs.
    for (int og = 0; og < OUTD / 4; ++og) {
        const float* cw = coefs + og * (4 * NB);   // uniform -> s_load batch
        f32x2 acc0 = basis[0] * cw[0 * NB];
        f32x2 acc1 = basis[0] * cw[1 * NB];
        f32x2 acc2 = basis[0] * cw[2 * NB];
        f32x2 acc3 = basis[0] * cw[3 * NB];
#pragma unroll
        for (int n = 1; n < NB; ++n) {
            const f32x2 c0 = {cw[0 * NB + n], cw[0 * NB + n]};
            const f32x2 c1 = {cw[1 * NB + n], cw[1 * NB + n]};
            const f32x2 c2 = {cw[2 * NB + n], cw[2 * NB + n]};
            const f32x2 c3 = {cw[3 * NB + n], cw[3 * NB + n]};
            acc0 = __builtin_elementwise_fma(basis[n], c0, acc0);
            acc1 = __builtin_elementwise_fma(basis[n], c1, acc1);
            acc2 = __builtin_elementwise_fma(basis[n], c2, acc2);
            acc3 = __builtin_elementwise_fma(basis[n], c3, acc3);
        }
        float* p0 = op + (size_t)(og * 4) * ostride;
        __builtin_nontemporal_store(acc0, (f32x2*)p0);
        __builtin_nontemporal_store(acc1, (f32x2*)(p0 + ostride));
        __builtin_nontemporal_store(acc2, (f32x2*)(p0 + 2 * ostride));
        __builtin_nontemporal_store(acc3, (f32x2*)(p0 + 3 * ostride));
    }
}

extern "C" void kernel_launch(void* const* d_in, const int* in_sizes, int n_in,
                              void* d_out, int out_size, void* d_ws, size_t ws_size,
                              hipStream_t stream) {
    const float* x      = (const float*)d_in[0];
    const float* conv_w = (const float*)d_in[1];
    const float* conv_b = (const float*)d_in[2];
    const float* coefs  = (const float*)d_in[3];
    float* out = (float*)d_out;

    const int blocks = BATCH * NWIN * (NSEQ / (256 * 2));  // 8*65*8 = 4160
    trf_kernel<<<blocks, 256, 0, stream>>>(x, conv_w, conv_b, coefs, out);
}

// Round 5
// 100.926 us; speedup vs baseline: 1.0931x; 1.0931x over previous
//
#include <hip/hip_runtime.h>
#include <math.h>

#define BATCH 8
#define NSEQ  4096
#define NWIN  65
#define OUTD  64
#define NB    21

typedef __attribute__((ext_vector_type(4))) float f32x4;

// out[b,o,w,s] = a(b,s) * ( const0*coefs[o,0] + sum_{n=1..10} scale*(sin(n*th)*coefs[o,2n-1] + cos(n*th)*coefs[o,2n]) )
// th = (2*pi/78) * c(b,s) * ((w+7) - bshift(b,s))
// Thread: 4 consecutive s-points x 16 outputs (o-split x4 across blocks).
// All 16 outputs get DEDICATED f32x4 accumulators -> no VGPR reuse across the
// store burst -> no vmcnt waits between compute and stores; stores drain while
// other waves compute. 8320 blocks (~10us each) for a smooth tail.
__global__ __launch_bounds__(256, 3) void trf_kernel(
    const float* __restrict__ x,        // (8,1,4096)
    const float* __restrict__ conv_w,   // (3,1,2)
    const float* __restrict__ conv_b,   // (3,)
    const float* __restrict__ coefs,    // (64,1,21)
    float* __restrict__ out)            // (8,64,65,4096)
{
    const int tid   = threadIdx.x;
    const int blk   = blockIdx.x;
    const int og    = blk & 3;           // output group: o = og*16 .. og*16+15
    const int chunk = (blk >> 2) & 3;    // 4 chunks of 1024 s each
    const int bw    = blk >> 4;
    const int w     = bw % NWIN;
    const int b     = bw / NWIN;
    const int s0    = chunk * 1024 + tid * 4;

    // conv weights: wave-uniform scalar loads
    const float w00 = conv_w[0], w01 = conv_w[1];
    const float w10 = conv_w[2], w11 = conv_w[3];
    const float w20 = conv_w[4], w21 = conv_w[5];
    const float cb0 = conv_b[0], cb1 = conv_b[1], cb2 = conv_b[2];

    const float* xb = x + (size_t)b * NSEQ;
    const f32x4 xq  = *(const f32x4*)(xb + s0);            // x[s0..s0+3], 16B aligned
    const float xm0 = (s0 > 0) ? xb[s0 - 1] : 0.0f;        // causal left-pad

    const float K      = 0.08055365778435367f;  // 2*pi/78
    const float SCALE  = 0.16012815380508713f;  // 1/sqrt(39)
    const float CONST0 = 0.11322770341445958f;  // 1/(sqrt(2)*sqrt(39))
    const float wl     = (float)(w + 7);

    f32x4 basis[NB];                                       // 84 VGPRs, static-indexed
#pragma unroll
    for (int p = 0; p < 4; ++p) {
        const float xm = (p == 0) ? xm0 : xq[p - 1];
        const float xc = xq[p];
        const float p0 = fmaf(xm, w00, fmaf(xc, w01, cb0));
        const float p1 = fmaf(xm, w10, fmaf(xc, w11, cb1));
        const float p2 = fmaf(xm, w20, fmaf(xc, w21, cb2));
        const float a  = fabsf(p0);
        const float bs = fminf(fmaxf(p1, -7.0f), 7.0f);
        const float c  = fminf(fmaxf(1.0f + p2, 0.5f), 1.4f);

        const float theta = K * c * (wl - bs);
        float sn, cn;
        __sincosf(theta, &sn, &cn);

        const float fa = a * SCALE;
        basis[0][p] = a * CONST0;
        const float twoc = 2.0f * cn;
        float sp = 0.0f, cp = 1.0f;      // sin(0), cos(0)
        float scur = sn, ccur = cn;      // sin(th), cos(th)
#pragma unroll
        for (int n = 1; n <= 10; ++n) {  // Chebyshev recurrence for sin/cos(n*th)
            basis[2 * n - 1][p] = fa * scur;
            basis[2 * n][p]     = fa * ccur;
            const float snew = fmaf(twoc, scur, -sp);
            const float cnew = fmaf(twoc, ccur, -cp);
            sp = scur; cp = ccur; scur = snew; ccur = cnew;
        }
    }

    // 16 dedicated accumulators, fully unrolled -> static register indexing
    const float* cwb = coefs + og * 16 * NB;   // uniform -> s_load batch
    f32x4 acc[16];
#pragma unroll
    for (int j = 0; j < 16; ++j) {
        const float* cw = cwb + j * NB;
        f32x4 a0 = basis[0] * cw[0];
#pragma unroll
        for (int n = 1; n < NB; ++n) {
            const float cs = cw[n];
            const f32x4 cv = {cs, cs, cs, cs};
            a0 = __builtin_elementwise_fma(basis[n], cv, a0);
        }
        acc[j] = a0;
    }

    // out index: ((b*64 + o)*65 + w)*4096 + s0 ; store burst, no reg reuse after
    float* op = out + ((size_t)(b * OUTD + og * 16) * NWIN + (size_t)w) * NSEQ + s0;
    const size_t ostride = (size_t)NWIN * NSEQ;
#pragma unroll
    for (int j = 0; j < 16; ++j) {
        __builtin_nontemporal_store(acc[j], (f32x4*)(op + (size_t)j * ostride));
    }
}

extern "C" void kernel_launch(void* const* d_in, const int* in_sizes, int n_in,
                              void* d_out, int out_size, void* d_ws, size_t ws_size,
                              hipStream_t stream) {
    const float* x      = (const float*)d_in[0];
    const float* conv_w = (const float*)d_in[1];
    const float* conv_b = (const float*)d_in[2];
    const float* coefs  = (const float*)d_in[3];
    float* out = (float*)d_out;

    const int blocks = BATCH * NWIN * 4 /*s-chunks*/ * 4 /*o-groups*/;  // 8320
    trf_kernel<<<blocks, 256, 0, stream>>>(x, conv_w, conv_b, coefs, out);
}

// Round 6
// 96.943 us; speedup vs baseline: 1.1380x; 1.0411x over previous
//
#include <hip/hip_runtime.h>
#include <math.h>

#define BATCH 8
#define NSEQ  4096
#define NWIN  65
#define OUTD  64
#define NB    21

typedef __attribute__((ext_vector_type(4))) float f32x4;

// out[b,o,w,s] = a(b,s) * ( const0*coefs[o,0] + sum_{n=1..10} scale*(sin(n*th)*coefs[o,2n-1] + cos(n*th)*coefs[o,2n]) )
// th = (2*pi/78) * c(b,s) * ((w+7) - bshift(b,s))
// Thread: 4 consecutive s-points x 16 outputs (o-split x4 across blocks).
// 16 DEDICATED accumulators (no vmcnt-forcing register reuse), but each NT
// store issues IMMEDIATELY after its 21-FMA chain -> store issue spread evenly
// through compute (anti-convoy), drain starts at t~0.
__global__ __launch_bounds__(256, 3) void trf_kernel(
    const float* __restrict__ x,        // (8,1,4096)
    const float* __restrict__ conv_w,   // (3,1,2)
    const float* __restrict__ conv_b,   // (3,)
    const float* __restrict__ coefs,    // (64,1,21)
    float* __restrict__ out)            // (8,64,65,4096)
{
    const int tid   = threadIdx.x;
    const int blk   = blockIdx.x;
    const int og    = blk & 3;           // output group: o = og*16 .. og*16+15
    const int chunk = (blk >> 2) & 3;    // 4 chunks of 1024 s each
    const int bw    = blk >> 4;
    const int w     = bw % NWIN;
    const int b     = bw / NWIN;
    const int s0    = chunk * 1024 + tid * 4;

    // conv weights: wave-uniform scalar loads
    const float w00 = conv_w[0], w01 = conv_w[1];
    const float w10 = conv_w[2], w11 = conv_w[3];
    const float w20 = conv_w[4], w21 = conv_w[5];
    const float cb0 = conv_b[0], cb1 = conv_b[1], cb2 = conv_b[2];

    const float* xb = x + (size_t)b * NSEQ;
    const f32x4 xq  = *(const f32x4*)(xb + s0);            // x[s0..s0+3], 16B aligned
    const float xm0 = (s0 > 0) ? xb[s0 - 1] : 0.0f;        // causal left-pad

    const float K      = 0.08055365778435367f;  // 2*pi/78
    const float SCALE  = 0.16012815380508713f;  // 1/sqrt(39)
    const float CONST0 = 0.11322770341445958f;  // 1/(sqrt(2)*sqrt(39))
    const float wl     = (float)(w + 7);

    f32x4 basis[NB];                                       // 84 VGPRs, static-indexed
#pragma unroll
    for (int p = 0; p < 4; ++p) {
        const float xm = (p == 0) ? xm0 : xq[p - 1];
        const float xc = xq[p];
        const float p0 = fmaf(xm, w00, fmaf(xc, w01, cb0));
        const float p1 = fmaf(xm, w10, fmaf(xc, w11, cb1));
        const float p2 = fmaf(xm, w20, fmaf(xc, w21, cb2));
        const float a  = fabsf(p0);
        const float bs = fminf(fmaxf(p1, -7.0f), 7.0f);
        const float c  = fminf(fmaxf(1.0f + p2, 0.5f), 1.4f);

        const float theta = K * c * (wl - bs);
        float sn, cn;
        __sincosf(theta, &sn, &cn);

        const float fa = a * SCALE;
        basis[0][p] = a * CONST0;
        const float twoc = 2.0f * cn;
        float sp = 0.0f, cp = 1.0f;      // sin(0), cos(0)
        float scur = sn, ccur = cn;      // sin(th), cos(th)
#pragma unroll
        for (int n = 1; n <= 10; ++n) {  // Chebyshev recurrence for sin/cos(n*th)
            basis[2 * n - 1][p] = fa * scur;
            basis[2 * n][p]     = fa * ccur;
            const float snew = fmaf(twoc, scur, -sp);
            const float cnew = fmaf(twoc, ccur, -cp);
            sp = scur; cp = ccur; scur = snew; ccur = cnew;
        }
    }

    // out index: ((b*64 + o)*65 + w)*4096 + s0
    float* op = out + ((size_t)(b * OUTD + og * 16) * NWIN + (size_t)w) * NSEQ + s0;
    const size_t ostride = (size_t)NWIN * NSEQ;

    const float* cwb = coefs + og * 16 * NB;   // uniform -> s_load batch
    f32x4 acc[16];                              // dedicated regs, no reuse
#pragma unroll
    for (int j = 0; j < 16; ++j) {
        const float* cw = cwb + j * NB;
        acc[j] = basis[0] * cw[0];
#pragma unroll
        for (int n = 1; n < NB; ++n) {
            const float cs = cw[n];
            const f32x4 cv = {cs, cs, cs, cs};
            acc[j] = __builtin_elementwise_fma(basis[n], cv, acc[j]);
        }
        // store NOW: spreads store issue through the compute phase
        __builtin_nontemporal_store(acc[j], (f32x4*)(op + (size_t)j * ostride));
    }
}

extern "C" void kernel_launch(void* const* d_in, const int* in_sizes, int n_in,
                              void* d_out, int out_size, void* d_ws, size_t ws_size,
                              hipStream_t stream) {
    const float* x      = (const float*)d_in[0];
    const float* conv_w = (const float*)d_in[1];
    const float* conv_b = (const float*)d_in[2];
    const float* coefs  = (const float*)d_in[3];
    float* out = (float*)d_out;

    const int blocks = BATCH * NWIN * 4 /*s-chunks*/ * 4 /*o-groups*/;  // 8320
    trf_kernel<<<blocks, 256, 0, stream>>>(x, conv_w, conv_b, coefs, out);
}